// Round 13
// baseline (113.094 us; speedup 1.0000x reference)
//
#include <hip/hip_runtime.h>
#include <hip/hip_bf16.h>

#define NB 32
#define NC 512
#define NT 2048
#define NL 80
static constexpr float kInvSigma2 = 0.1f;  // 1/SIGMA2

typedef __attribute__((ext_vector_type(8))) __bf16 bf16x8;
typedef __attribute__((ext_vector_type(4))) float f32x4;

// ---------------------------------------------------------------------------
// W1 fp32 -> bf16, packed MFMA-tile-contiguous:
// w1p[o>>4][c>>5][o&15][c&31]  (16o x 32c tile = 1KB = one wave A-load).
// ---------------------------------------------------------------------------
__global__ __launch_bounds__(256) void k_w1p(const float* __restrict__ w1,
                                             __hip_bfloat16* __restrict__ w1p) {
  const int q = blockIdx.x * 256 + threadIdx.x;  // 8-elem chunk id
  const int c_lo = (q & 3) << 3;
  const int o_lo = (q >> 2) & 15;
  const int c5 = (q >> 6) & 15;
  const int o4 = q >> 10;
  const int o = (o4 << 4) + o_lo;
  const int c = (c5 << 5) + c_lo;
  const float4 p0 = *reinterpret_cast<const float4*>(&w1[o * NC + c]);
  const float4 p1 = *reinterpret_cast<const float4*>(&w1[o * NC + c + 4]);
  bf16x8 v;
  v[0] = (__bf16)p0.x; v[1] = (__bf16)p0.y;
  v[2] = (__bf16)p0.z; v[3] = (__bf16)p0.w;
  v[4] = (__bf16)p1.x; v[5] = (__bf16)p1.y;
  v[6] = (__bf16)p1.z; v[7] = (__bf16)p1.w;
  *reinterpret_cast<bf16x8*>(&w1p[(size_t)q * 8]) = v;
}

// ---------------------------------------------------------------------------
// MFMA g-kernel v11 = r10 structure (verified no-spill, VGPR=60) with the
// x staging loads marked NON-TEMPORAL: the 128 KB/block x stream was
// evicting the 512 KB w1p from the per-XCD L2 (64 blocks x 128 KB = 8 MB
// streaming through 4 MB), forcing the 64 A-loads/wave out to L3 (~31
// cy/instr average stall). nt keeps w1p L2-resident.
// Swizzle granule (c>>3)^(t&7)^((t>>3)&7) on both sides (verified r8-r10).
// ---------------------------------------------------------------------------
__global__ __launch_bounds__(512, 4) void k_g_mfma(
    const float* __restrict__ x, const __hip_bfloat16* __restrict__ w1p,
    const float* __restrict__ b1, const float* __restrict__ w2,
    const float* __restrict__ b2, float* __restrict__ g) {
  __shared__ __hip_bfloat16 bs[64 * 512];  // 64 KB
  __shared__ float pws[8][64];
  const int blk = blockIdx.x;
  const int b = blk >> 5;
  const int t0 = (blk & 31) << 6;
  const int tid = threadIdx.x;
  const int w = tid >> 6;          // wave id 0..7
  const int lane = tid & 63;
  const int ln = tid & 15;
  const int kg = lane >> 4;
  const int ob = w << 6;           // wave's o base (64 o per wave)

  // ---- fused staging: relu(x) fp32 [c][t] -> bf16 swizzled [t][c] in LDS
  //      x loads are NON-TEMPORAL (streaming; keep w1p in L2)
  {
    const int tl = (tid & 15) << 2;  // 4 consecutive t
    const int cp = (tid >> 4) << 1;  // even c offset 0..62
    const float* xb = x + (size_t)b * NC * NT + t0;
#pragma unroll
    for (int i = 0; i < 8; ++i) {
      const int c = (i << 6) + cp;   // rows c and c+1
      const f32x4 va = __builtin_nontemporal_load(
          reinterpret_cast<const f32x4*>(&xb[(size_t)c * NT + tl]));
      const f32x4 vb = __builtin_nontemporal_load(
          reinterpret_cast<const f32x4*>(&xb[(size_t)(c + 1) * NT + tl]));
#pragma unroll
      for (int j = 0; j < 4; ++j) {
        const int t = tl + j;
        const __hip_bfloat16 lo = __float2bfloat16(fmaxf(va[j], 0.f));
        const __hip_bfloat16 hi = __float2bfloat16(fmaxf(vb[j], 0.f));
        const unsigned pk =
            ((unsigned)*reinterpret_cast<const unsigned short*>(&hi) << 16) |
            *reinterpret_cast<const unsigned short*>(&lo);
        const int gran = ((c >> 3) ^ (t & 7) ^ ((t >> 3) & 7)) & 7;
        const int base = (c >> 3) & ~7;  // upper granule bits pass through
        *reinterpret_cast<unsigned*>(
            (char*)bs + (t << 10) +
            (((base | gran) << 4) | ((c & 7) << 1))) = pk;
      }
    }
  }
  __syncthreads();

  f32x4 acc[4][4];  // [ot][nt]
#pragma unroll
  for (int ot = 0; ot < 4; ++ot)
#pragma unroll
    for (int nt = 0; nt < 4; ++nt) acc[ot][nt] = (f32x4){0.f, 0.f, 0.f, 0.f};

  int rowb[4], xm[4];
#pragma unroll
  for (int nt = 0; nt < 4; ++nt) {
    const int tr = (nt << 4) + ln;
    rowb[nt] = tr << 10;                               // byte row base
    xm[nt] = (((tr & 7) ^ ((tr >> 3) & 7)) & 7) << 4;  // swizzle mask
  }
  // packed A: wave w owns o4-tiles [4w, 4w+4); lane (ln,kg) reads
  // tile_base + ln*32 + kg*8 elems; tile (ot,ks) at ((4w+ot)*16 + ks)*512.
  const __hip_bfloat16* abase =
      w1p + ((size_t)w << 15) + (ln << 5) + (kg << 3);
  const char* bsb = (const char*)bs;

#pragma unroll 4
  for (int ks = 0; ks < 16; ++ks) {
    const int gb = (ks << 6) + (kg << 4);  // byte col in B row
    bf16x8 bfrag[4];
#pragma unroll
    for (int nt = 0; nt < 4; ++nt)
      bfrag[nt] = *reinterpret_cast<const bf16x8*>(
          bsb + rowb[nt] + (gb ^ xm[nt]));
    __builtin_amdgcn_s_setprio(1);
#pragma unroll
    for (int ot = 0; ot < 4; ++ot) {
      const bf16x8 af = *reinterpret_cast<const bf16x8*>(
          abase + (ot << 13) + (ks << 9));
#pragma unroll
      for (int nt = 0; nt < 4; ++nt)
        acc[ot][nt] = __builtin_amdgcn_mfma_f32_16x16x32_bf16(
            af, bfrag[nt], acc[ot][nt], 0, 0, 0);
    }
    __builtin_amdgcn_s_setprio(0);
  }

  // epilogue: p_partial[t] = sum_{o in wave} w2[o]*relu(h+b1[o])
  float pl[4] = {0.f, 0.f, 0.f, 0.f};
#pragma unroll
  for (int ot = 0; ot < 4; ++ot) {
    const int o4 = ob + (ot << 4) + (kg << 2);
    const float4 b1v = *reinterpret_cast<const float4*>(&b1[o4]);
    const float4 w2v = *reinterpret_cast<const float4*>(&w2[o4]);
#pragma unroll
    for (int nt = 0; nt < 4; ++nt) {
      pl[nt] = fmaf(w2v.x, fmaxf(acc[ot][nt][0] + b1v.x, 0.f), pl[nt]);
      pl[nt] = fmaf(w2v.y, fmaxf(acc[ot][nt][1] + b1v.y, 0.f), pl[nt]);
      pl[nt] = fmaf(w2v.z, fmaxf(acc[ot][nt][2] + b1v.z, 0.f), pl[nt]);
      pl[nt] = fmaf(w2v.w, fmaxf(acc[ot][nt][3] + b1v.w, 0.f), pl[nt]);
    }
  }
#pragma unroll
  for (int nt = 0; nt < 4; ++nt) {
    pl[nt] += __shfl_xor(pl[nt], 16, 64);
    pl[nt] += __shfl_xor(pl[nt], 32, 64);
  }
  if (kg == 0) {
#pragma unroll
    for (int nt = 0; nt < 4; ++nt) pws[w][(nt << 4) + ln] = pl[nt];
  }
  __syncthreads();
  if (tid < 64) {
    float s = b2[0];
#pragma unroll
    for (int i = 0; i < 8; ++i) s += pws[i][tid];
    g[b * NT + t0 + tid] = 1.f / (1.f + __expf(-s));
  }
}

// ---------------------------------------------------------------------------
// Fallback g-kernel (VALU path).
// ---------------------------------------------------------------------------
__global__ __launch_bounds__(256) void k_g_slow(const float* __restrict__ x,
                                                const float* __restrict__ w1,
                                                const float* __restrict__ b1,
                                                const float* __restrict__ w2,
                                                const float* __restrict__ b2,
                                                float* __restrict__ g) {
  __shared__ __hip_bfloat16 xs[NC][64];
  const int blk = blockIdx.x;
  const int b = blk >> 5;
  const int t0 = (blk & 31) << 6;
  const int tid = threadIdx.x;
  {
    const int tl = (tid & 15) << 2;
    const int c0 = tid >> 4;
    for (int c = c0; c < NC; c += 16) {
      const float4 v = *reinterpret_cast<const float4*>(
          &x[((size_t)b * NC + c) * NT + t0 + tl]);
      xs[c][tl + 0] = __float2bfloat16(fmaxf(v.x, 0.f));
      xs[c][tl + 1] = __float2bfloat16(fmaxf(v.y, 0.f));
      xs[c][tl + 2] = __float2bfloat16(fmaxf(v.z, 0.f));
      xs[c][tl + 3] = __float2bfloat16(fmaxf(v.w, 0.f));
    }
  }
  __syncthreads();
  const int og = tid >> 6;
  const int t = tid & 63;
  float gacc = 0.f;
  for (int pass = 0; pass < 16; ++pass) {
    const int o0 = (og << 7) + (pass << 3);
    float h[8];
#pragma unroll
    for (int j = 0; j < 8; ++j) h[j] = b1[o0 + j];
    const float* wrow = w1 + (size_t)o0 * NC;
#pragma unroll 4
    for (int c = 0; c < NC; ++c) {
      const float xv = __bfloat162float(xs[c][t]);
#pragma unroll
      for (int j = 0; j < 8; ++j) h[j] = fmaf(wrow[j * NC + c], xv, h[j]);
    }
    float p = 0.f;
#pragma unroll
    for (int j = 0; j < 8; ++j) p = fmaf(w2[o0 + j], fmaxf(h[j], 0.f), p);
    gacc += p;
  }
  __syncthreads();
  float* gr = reinterpret_cast<float*>(&xs[0][0]);
  gr[og * 64 + t] = gacc;
  __syncthreads();
  if (tid < 64) {
    const float s = gr[tid] + gr[64 + tid] + gr[128 + tid] + gr[192 + tid] + b2[0];
    g[b * NT + t0 + tid] = 1.f / (1.f + __expf(-s));
  }
}

// ---------------------------------------------------------------------------
// Per-b inclusive scan of g; centers = cum - 0.5*g; aligned_lengths output.
// ---------------------------------------------------------------------------
__global__ __launch_bounds__(256) void k_scan(const float* __restrict__ g,
                                              const int* __restrict__ len_fea,
                                              float* __restrict__ centers,
                                              float* __restrict__ out_len) {
  const int b = blockIdx.x;
  const int tid = threadIdx.x;
  const float* gb = g + b * NT;
  float v[8];
  {
    const float4 p0 = *reinterpret_cast<const float4*>(&gb[tid * 8]);
    const float4 p1 = *reinterpret_cast<const float4*>(&gb[tid * 8 + 4]);
    v[0] = p0.x; v[1] = p0.y; v[2] = p0.z; v[3] = p0.w;
    v[4] = p1.x; v[5] = p1.y; v[6] = p1.z; v[7] = p1.w;
  }
  float s = 0.f;
#pragma unroll
  for (int j = 0; j < 8; ++j) s += v[j];
  float wscan = s;
  const int lane = tid & 63, wid = tid >> 6;
#pragma unroll
  for (int off = 1; off < 64; off <<= 1) {
    const float o = __shfl_up(wscan, (unsigned)off, 64);
    if (lane >= off) wscan += o;
  }
  __shared__ float wsum[4];
  if (lane == 63) wsum[wid] = wscan;
  __syncthreads();
  float base = 0.f;
#pragma unroll
  for (int i = 0; i < 4; ++i)
    if (i < wid) base += wsum[i];
  float run = base + wscan - s;
  const int li = len_fea[b] - 1;
#pragma unroll
  for (int j = 0; j < 8; ++j) {
    const int t = tid * 8 + j;
    run += v[j];
    centers[b * NT + t] = run - 0.5f * v[j];
    if (t == li) out_len[b] = run;
  }
}

// ---------------------------------------------------------------------------
// Fused softmax stats + w materialization (bf16 [B][NL][NT]).
// ---------------------------------------------------------------------------
__global__ __launch_bounds__(256) void k_wstats(
    const float* __restrict__ centers, const int* __restrict__ len_fea,
    __hip_bfloat16* __restrict__ wbf) {
  const int b = blockIdx.x / NL;
  const int l = blockIdx.x % NL;
  const int tid = threadIdx.x;
  const int len = len_fea[b];
  const float pos = 0.5f + (float)l;
  const float* cb = centers + b * NT;
  const int t0 = tid * 8;

  float cv[8];
  {
    const float4 p0 = *reinterpret_cast<const float4*>(&cb[t0]);
    const float4 p1 = *reinterpret_cast<const float4*>(&cb[t0 + 4]);
    cv[0] = p0.x; cv[1] = p0.y; cv[2] = p0.z; cv[3] = p0.w;
    cv[4] = p1.x; cv[5] = p1.y; cv[6] = p1.z; cv[7] = p1.w;
  }
  float lg[8];
  float m = -3.0e38f;
#pragma unroll
  for (int j = 0; j < 8; ++j) {
    if (t0 + j < len) {
      const float d = cv[j] - pos;
      lg[j] = -d * d * kInvSigma2;
      m = fmaxf(m, lg[j]);
    } else {
      lg[j] = -3.0e38f;
    }
  }
  const int lane = tid & 63, wid = tid >> 6;
#pragma unroll
  for (int off = 32; off > 0; off >>= 1) m = fmaxf(m, __shfl_xor(m, off, 64));
  __shared__ float redm[4];
  if (lane == 0) redm[wid] = m;
  __syncthreads();
  const float M = fmaxf(fmaxf(redm[0], redm[1]), fmaxf(redm[2], redm[3]));

  float e[8];
  float ssum = 0.f;
#pragma unroll
  for (int j = 0; j < 8; ++j) {
    e[j] = (t0 + j < len) ? __expf(lg[j] - M) : 0.f;
    ssum += e[j];
  }
#pragma unroll
  for (int off = 32; off > 0; off >>= 1) ssum += __shfl_xor(ssum, off, 64);
  __shared__ float reds[4];
  if (lane == 0) reds[wid] = ssum;
  __syncthreads();
  const float rinv = 1.f / (reds[0] + reds[1] + reds[2] + reds[3]);

  bf16x8 o;
#pragma unroll
  for (int j = 0; j < 8; ++j) o[j] = (__bf16)(e[j] * rinv);
  *reinterpret_cast<bf16x8*>(&wbf[((size_t)b * NL + l) * NT + t0]) = o;
}

// ---------------------------------------------------------------------------
// MFMA out-kernel: out[b,l,c] = sum_t w[l,t]*x[c,t].
// Block = 4 waves, K(t)-split 4-way, LDS reduce (padded).
// ---------------------------------------------------------------------------
__global__ __launch_bounds__(256) void k_out_mfma(
    const float* __restrict__ x, const __hip_bfloat16* __restrict__ wbf,
    float* __restrict__ out) {
  __shared__ float red[3][64][41];
  const int blk = blockIdx.x;
  const int b = blk >> 4;
  const int c0 = (blk & 15) << 5;
  const int tid = threadIdx.x;
  const int w = tid >> 6;
  const int lane = tid & 63;
  const int ln = tid & 15;
  const int kg = lane >> 4;
  const int tbase = w << 9;

  f32x4 acc[5][2];
#pragma unroll
  for (int lt = 0; lt < 5; ++lt)
#pragma unroll
    for (int nt = 0; nt < 2; ++nt) acc[lt][nt] = (f32x4){0.f, 0.f, 0.f, 0.f};

  const __hip_bfloat16* abase =
      wbf + ((size_t)b * NL + ln) * NT + tbase + (kg << 3);
  const float* bbase = x + ((size_t)b * NC + c0 + ln) * NT + tbase + (kg << 3);

#pragma unroll 4
  for (int ks = 0; ks < 16; ++ks) {
    const int ck = ks << 5;
    bf16x8 bfrag[2];
#pragma unroll
    for (int nt = 0; nt < 2; ++nt) {
      const float4 p0 =
          *reinterpret_cast<const float4*>(bbase + nt * 16 * NT + ck);
      const float4 p1 =
          *reinterpret_cast<const float4*>(bbase + nt * 16 * NT + ck + 4);
      bf16x8 v;
      v[0] = (__bf16)p0.x; v[1] = (__bf16)p0.y;
      v[2] = (__bf16)p0.z; v[3] = (__bf16)p0.w;
      v[4] = (__bf16)p1.x; v[5] = (__bf16)p1.y;
      v[6] = (__bf16)p1.z; v[7] = (__bf16)p1.w;
      bfrag[nt] = v;
    }
#pragma unroll
    for (int lt = 0; lt < 5; ++lt) {
      const bf16x8 af =
          *reinterpret_cast<const bf16x8*>(abase + lt * 16 * NT + ck);
      acc[lt][0] = __builtin_amdgcn_mfma_f32_16x16x32_bf16(af, bfrag[0],
                                                           acc[lt][0], 0, 0, 0);
      acc[lt][1] = __builtin_amdgcn_mfma_f32_16x16x32_bf16(af, bfrag[1],
                                                           acc[lt][1], 0, 0, 0);
    }
  }

  if (w > 0) {
#pragma unroll
    for (int lt = 0; lt < 5; ++lt)
#pragma unroll
      for (int nt = 0; nt < 2; ++nt)
#pragma unroll
        for (int j = 0; j < 4; ++j)
          red[w - 1][lane][lt * 8 + nt * 4 + j] = acc[lt][nt][j];
  }
  __syncthreads();
  if (w == 0) {
#pragma unroll
    for (int lt = 0; lt < 5; ++lt)
#pragma unroll
      for (int nt = 0; nt < 2; ++nt)
#pragma unroll
        for (int j = 0; j < 4; ++j) {
          float s = acc[lt][nt][j];
#pragma unroll
          for (int i = 0; i < 3; ++i) s += red[i][lane][lt * 8 + nt * 4 + j];
          const int l = lt * 16 + (kg << 2) + j;
          out[((size_t)b * NL + l) * NC + c0 + nt * 16 + ln] = s;
        }
  }
}

// ---------------------------------------------------------------------------
// Fallback stats + out (VALU path).
// ---------------------------------------------------------------------------
__global__ __launch_bounds__(256) void k_stats(const float* __restrict__ centers,
                                               const int* __restrict__ len_fea,
                                               float* __restrict__ rmax,
                                               float* __restrict__ rinv) {
  const int b = blockIdx.x / NL;
  const int l = blockIdx.x % NL;
  const int tid = threadIdx.x;
  const int len = len_fea[b];
  const float pos = 0.5f + (float)l;
  const float* cb = centers + b * NT;
  float lg[8];
  float m = -3.0e38f;
  const int t0 = tid * 8;
#pragma unroll
  for (int j = 0; j < 8; ++j) {
    const int t = t0 + j;
    if (t < len) {
      const float d = cb[t] - pos;
      lg[j] = -d * d * kInvSigma2;
      m = fmaxf(m, lg[j]);
    } else {
      lg[j] = -3.0e38f;
    }
  }
  const int lane = tid & 63, wid = tid >> 6;
#pragma unroll
  for (int off = 32; off > 0; off >>= 1) m = fmaxf(m, __shfl_xor(m, off, 64));
  __shared__ float redm[4];
  if (lane == 0) redm[wid] = m;
  __syncthreads();
  const float M = fmaxf(fmaxf(redm[0], redm[1]), fmaxf(redm[2], redm[3]));
  float ssum = 0.f;
#pragma unroll
  for (int j = 0; j < 8; ++j) {
    if (t0 + j < len) ssum += __expf(lg[j] - M);
  }
#pragma unroll
  for (int off = 32; off > 0; off >>= 1) ssum += __shfl_xor(ssum, off, 64);
  __shared__ float reds[4];
  if (lane == 0) reds[wid] = ssum;
  __syncthreads();
  if (tid == 0) {
    const float S = reds[0] + reds[1] + reds[2] + reds[3];
    rmax[blockIdx.x] = M;
    rinv[blockIdx.x] = 1.f / S;
  }
}

__global__ __launch_bounds__(128) void k_out(const float* __restrict__ x,
                                             const int* __restrict__ len_fea,
                                             const float* __restrict__ centers,
                                             const float* __restrict__ rmax,
                                             const float* __restrict__ rinv,
                                             float* __restrict__ out) {
  __shared__ float xsh[128][65];
  __shared__ float wsh[20][64];
  const int blk = blockIdx.x;
  const int b = blk >> 4;
  const int l0 = ((blk >> 2) & 3) * 20;
  const int c0 = (blk & 3) * 128;
  const int tid = threadIdx.x;
  const int len = len_fea[b];
  float acc[20];
#pragma unroll
  for (int l = 0; l < 20; ++l) acc[l] = 0.f;

  for (int t0 = 0; t0 < NT; t0 += 64) {
    __syncthreads();
    {
      const int tl = (tid & 15) << 2;
      const int r0 = tid >> 4;
      for (int r = r0; r < 128; r += 8) {
        const float4 v = *reinterpret_cast<const float4*>(
            &x[((size_t)b * NC + c0 + r) * NT + t0 + tl]);
        float* p = &xsh[r][tl];
        p[0] = v.x; p[1] = v.y; p[2] = v.z; p[3] = v.w;
      }
    }
#pragma unroll
    for (int k = 0; k < 10; ++k) {
      const int idx = k * 128 + tid;
      const int l = idx >> 6;
      const int tt = idx & 63;
      float wv = 0.f;
      if (t0 + tt < len) {
        const float d = centers[b * NT + t0 + tt] - (0.5f + (float)(l0 + l));
        wv = __expf(-d * d * kInvSigma2 - rmax[b * NL + l0 + l]) *
             rinv[b * NL + l0 + l];
      }
      wsh[l][tt] = wv;
    }
    __syncthreads();
#pragma unroll 4
    for (int tt = 0; tt < 64; ++tt) {
      const float xv = xsh[tid][tt];
#pragma unroll
      for (int l = 0; l < 20; ++l) acc[l] = fmaf(wsh[l][tt], xv, acc[l]);
    }
  }
#pragma unroll
  for (int l = 0; l < 20; ++l)
    out[((size_t)b * NL + l0 + l) * NC + c0 + tid] = acc[l];
}

// ---------------------------------------------------------------------------
extern "C" void kernel_launch(void* const* d_in, const int* in_sizes, int n_in,
                              void* d_out, int out_size, void* d_ws, size_t ws_size,
                              hipStream_t stream) {
  const float* x = (const float*)d_in[0];
  const int* len_fea = (const int*)d_in[1];
  const float* w1 = (const float*)d_in[2];
  const float* b1 = (const float*)d_in[3];
  const float* w2 = (const float*)d_in[4];
  const float* b2 = (const float*)d_in[5];

  float* out = (float*)d_out;                   // [NB][NL][NC]
  float* out_len = out + (size_t)NB * NL * NC;  // [NB]

  float* ws = (float*)d_ws;
  float* g = ws;                                // [NB][NT]
  float* centers = ws + NB * NT;                // [NB][NT]
  float* rmax = ws + 2 * NB * NT;               // [NB*NL] (fallback)
  float* rinv = rmax + NB * NL;                 // [NB*NL] (fallback)
  __hip_bfloat16* w1p = (__hip_bfloat16*)(rinv + NB * NL);    // [512*512] packed
  __hip_bfloat16* wbf = w1p + (size_t)NC * NC;                // [NB][NL][NT]

  const size_t need_mid = (size_t)(2 * NB * NT + 2 * NB * NL) * 4 +
                          (size_t)NC * NC * 2;
  const size_t need_full = need_mid + (size_t)NB * NL * NT * 2;

  if (ws_size >= need_full) {
    k_w1p<<<(NC * NC) / 2048, 256, 0, stream>>>(w1, w1p);
    k_g_mfma<<<NB * 32, 512, 0, stream>>>(x, w1p, b1, w2, b2, g);
    k_scan<<<NB, 256, 0, stream>>>(g, len_fea, centers, out_len);
    k_wstats<<<NB * NL, 256, 0, stream>>>(centers, len_fea, wbf);
    k_out_mfma<<<NB * 16, 256, 0, stream>>>(x, wbf, out);
  } else if (ws_size >= need_mid) {
    k_w1p<<<(NC * NC) / 2048, 256, 0, stream>>>(w1, w1p);
    k_g_mfma<<<NB * 32, 512, 0, stream>>>(x, w1p, b1, w2, b2, g);
    k_scan<<<NB, 256, 0, stream>>>(g, len_fea, centers, out_len);
    k_stats<<<NB * NL, 256, 0, stream>>>(centers, len_fea, rmax, rinv);
    k_out<<<NB * 16, 128, 0, stream>>>(x, len_fea, centers, rmax, rinv, out);
  } else {
    k_g_slow<<<NB * 32, 256, 0, stream>>>(x, w1, b1, w2, b2, g);
    k_scan<<<NB, 256, 0, stream>>>(g, len_fea, centers, out_len);
    k_stats<<<NB * NL, 256, 0, stream>>>(centers, len_fea, rmax, rinv);
    k_out<<<NB * 16, 128, 0, stream>>>(x, len_fea, centers, rmax, rinv, out);
  }
}

// Round 14
// 102.863 us; speedup vs baseline: 1.0995x; 1.0995x over previous
//
#include <hip/hip_runtime.h>
#include <hip/hip_bf16.h>

#define NB 32
#define NC 512
#define NT 2048
#define NL 80
static constexpr float kInvSigma2 = 0.1f;  // 1/SIGMA2

typedef __attribute__((ext_vector_type(8))) __bf16 bf16x8;
typedef __attribute__((ext_vector_type(4))) float f32x4;

// ---------------------------------------------------------------------------
// W1 fp32 -> bf16, packed MFMA-tile-contiguous:
// w1p[o>>4][c>>5][o&15][c&31]  (16o x 32c tile = 1KB = one wave A-load).
// ---------------------------------------------------------------------------
__global__ __launch_bounds__(256) void k_w1p(const float* __restrict__ w1,
                                             __hip_bfloat16* __restrict__ w1p) {
  const int q = blockIdx.x * 256 + threadIdx.x;  // 8-elem chunk id
  const int c_lo = (q & 3) << 3;
  const int o_lo = (q >> 2) & 15;
  const int c5 = (q >> 6) & 15;
  const int o4 = q >> 10;
  const int o = (o4 << 4) + o_lo;
  const int c = (c5 << 5) + c_lo;
  const float4 p0 = *reinterpret_cast<const float4*>(&w1[o * NC + c]);
  const float4 p1 = *reinterpret_cast<const float4*>(&w1[o * NC + c + 4]);
  bf16x8 v;
  v[0] = (__bf16)p0.x; v[1] = (__bf16)p0.y;
  v[2] = (__bf16)p0.z; v[3] = (__bf16)p0.w;
  v[4] = (__bf16)p1.x; v[5] = (__bf16)p1.y;
  v[6] = (__bf16)p1.z; v[7] = (__bf16)p1.w;
  *reinterpret_cast<bf16x8*>(&w1p[(size_t)q * 8]) = v;
}

// ---------------------------------------------------------------------------
// MFMA g-kernel v12: 128-t tile (2x A amortization).
// grid = NB*16 = 512 blocks x 512 thr, 1 block/CU (LDS 132 KB).
// Each A-fragment load now feeds 8 MFMAs (was 4); W1 L2 traffic halves;
// 2 block-generations/CU instead of 4. Staging = r10's conflict-free
// mapping (16 t-groups x 4 c-pairs/wave) over two t-halves; swizzle
// granule (c>>3)^(t&7)^((t>>3)&7) both sides (verified r8-r13).
// Normal x loads (keep x L3-resident for k_out; nt lesson from r13).
// ---------------------------------------------------------------------------
__global__ __launch_bounds__(512, 2) void k_g_mfma(
    const float* __restrict__ x, const __hip_bfloat16* __restrict__ w1p,
    const float* __restrict__ b1, const float* __restrict__ w2,
    const float* __restrict__ b2, float* __restrict__ g) {
  __shared__ __hip_bfloat16 bs[128 * 512];  // 128 KB
  __shared__ float pws[8][128];             // 4 KB
  const int blk = blockIdx.x;
  const int b = blk >> 4;
  const int t0 = (blk & 15) << 7;  // 128 t per block
  const int tid = threadIdx.x;
  const int w = tid >> 6;          // wave id 0..7
  const int lane = tid & 63;
  const int ln = tid & 15;
  const int kg = lane >> 4;
  const int ob = w << 6;           // wave's o base (64 o per wave)

  // ---- fused staging: relu(x) fp32 [c][t] -> bf16 swizzled [t][c] in LDS
  {
    const int tl = (tid & 15) << 2;  // 4 consecutive t (within 64-half)
    const int cp = (tid >> 4) << 1;  // even c offset 0..62
    const float* xb = x + (size_t)b * NC * NT + t0;
#pragma unroll
    for (int h = 0; h < 2; ++h) {      // t-halves 0..63, 64..127
      const int th = tl + (h << 6);
#pragma unroll
      for (int i = 0; i < 8; ++i) {
        const int c = (i << 6) + cp;   // rows c and c+1
        const float4 va =
            *reinterpret_cast<const float4*>(&xb[(size_t)c * NT + th]);
        const float4 vb =
            *reinterpret_cast<const float4*>(&xb[(size_t)(c + 1) * NT + th]);
        const float fa[4] = {va.x, va.y, va.z, va.w};
        const float fb[4] = {vb.x, vb.y, vb.z, vb.w};
#pragma unroll
        for (int j = 0; j < 4; ++j) {
          const int t = th + j;
          const __hip_bfloat16 lo = __float2bfloat16(fmaxf(fa[j], 0.f));
          const __hip_bfloat16 hi = __float2bfloat16(fmaxf(fb[j], 0.f));
          const unsigned pk =
              ((unsigned)*reinterpret_cast<const unsigned short*>(&hi) << 16) |
              *reinterpret_cast<const unsigned short*>(&lo);
          const int gran = ((c >> 3) ^ (t & 7) ^ ((t >> 3) & 7)) & 7;
          const int base = (c >> 3) & ~7;  // upper granule bits pass through
          *reinterpret_cast<unsigned*>(
              (char*)bs + (t << 10) +
              (((base | gran) << 4) | ((c & 7) << 1))) = pk;
        }
      }
    }
  }
  __syncthreads();

  f32x4 acc[4][8];  // [ot][nt] -- 128 accumulator regs
#pragma unroll
  for (int ot = 0; ot < 4; ++ot)
#pragma unroll
    for (int nt = 0; nt < 8; ++nt) acc[ot][nt] = (f32x4){0.f, 0.f, 0.f, 0.f};

  int rowb[8], xm[8];
#pragma unroll
  for (int nt = 0; nt < 8; ++nt) {
    const int tr = (nt << 4) + ln;
    rowb[nt] = tr << 10;                               // byte row base
    xm[nt] = (((tr & 7) ^ ((tr >> 3) & 7)) & 7) << 4;  // swizzle mask
  }
  // packed A: wave w owns o4-tiles [4w, 4w+4); lane (ln,kg) reads
  // tile_base + ln*32 + kg*8 elems; tile (ot,ks) at ((4w+ot)*16 + ks)*512.
  const __hip_bfloat16* abase =
      w1p + ((size_t)w << 15) + (ln << 5) + (kg << 3);
  const char* bsb = (const char*)bs;

#pragma unroll 2
  for (int ks = 0; ks < 16; ++ks) {
    const int gb = (ks << 6) + (kg << 4);  // byte col in B row
    bf16x8 bfrag[8];
#pragma unroll
    for (int nt = 0; nt < 8; ++nt)
      bfrag[nt] = *reinterpret_cast<const bf16x8*>(
          bsb + rowb[nt] + (gb ^ xm[nt]));
    __builtin_amdgcn_s_setprio(1);
#pragma unroll
    for (int ot = 0; ot < 4; ++ot) {
      const bf16x8 af = *reinterpret_cast<const bf16x8*>(
          abase + (ot << 13) + (ks << 9));
#pragma unroll
      for (int nt = 0; nt < 8; ++nt)
        acc[ot][nt] = __builtin_amdgcn_mfma_f32_16x16x32_bf16(
            af, bfrag[nt], acc[ot][nt], 0, 0, 0);
    }
    __builtin_amdgcn_s_setprio(0);
  }

  // epilogue: p_partial[t] = sum_{o in wave} w2[o]*relu(h+b1[o])
  float pl[8] = {0.f, 0.f, 0.f, 0.f, 0.f, 0.f, 0.f, 0.f};
#pragma unroll
  for (int ot = 0; ot < 4; ++ot) {
    const int o4 = ob + (ot << 4) + (kg << 2);
    const float4 b1v = *reinterpret_cast<const float4*>(&b1[o4]);
    const float4 w2v = *reinterpret_cast<const float4*>(&w2[o4]);
#pragma unroll
    for (int nt = 0; nt < 8; ++nt) {
      pl[nt] = fmaf(w2v.x, fmaxf(acc[ot][nt][0] + b1v.x, 0.f), pl[nt]);
      pl[nt] = fmaf(w2v.y, fmaxf(acc[ot][nt][1] + b1v.y, 0.f), pl[nt]);
      pl[nt] = fmaf(w2v.z, fmaxf(acc[ot][nt][2] + b1v.z, 0.f), pl[nt]);
      pl[nt] = fmaf(w2v.w, fmaxf(acc[ot][nt][3] + b1v.w, 0.f), pl[nt]);
    }
  }
#pragma unroll
  for (int nt = 0; nt < 8; ++nt) {
    pl[nt] += __shfl_xor(pl[nt], 16, 64);
    pl[nt] += __shfl_xor(pl[nt], 32, 64);
  }
  if (kg == 0) {
#pragma unroll
    for (int nt = 0; nt < 8; ++nt) pws[w][(nt << 4) + ln] = pl[nt];
  }
  __syncthreads();
  if (tid < 128) {
    float s = b2[0];
#pragma unroll
    for (int i = 0; i < 8; ++i) s += pws[i][tid];
    g[b * NT + t0 + tid] = 1.f / (1.f + __expf(-s));
  }
}

// ---------------------------------------------------------------------------
// Fallback g-kernel (VALU path).
// ---------------------------------------------------------------------------
__global__ __launch_bounds__(256) void k_g_slow(const float* __restrict__ x,
                                                const float* __restrict__ w1,
                                                const float* __restrict__ b1,
                                                const float* __restrict__ w2,
                                                const float* __restrict__ b2,
                                                float* __restrict__ g) {
  __shared__ __hip_bfloat16 xs[NC][64];
  const int blk = blockIdx.x;
  const int b = blk >> 5;
  const int t0 = (blk & 31) << 6;
  const int tid = threadIdx.x;
  {
    const int tl = (tid & 15) << 2;
    const int c0 = tid >> 4;
    for (int c = c0; c < NC; c += 16) {
      const float4 v = *reinterpret_cast<const float4*>(
          &x[((size_t)b * NC + c) * NT + t0 + tl]);
      xs[c][tl + 0] = __float2bfloat16(fmaxf(v.x, 0.f));
      xs[c][tl + 1] = __float2bfloat16(fmaxf(v.y, 0.f));
      xs[c][tl + 2] = __float2bfloat16(fmaxf(v.z, 0.f));
      xs[c][tl + 3] = __float2bfloat16(fmaxf(v.w, 0.f));
    }
  }
  __syncthreads();
  const int og = tid >> 6;
  const int t = tid & 63;
  float gacc = 0.f;
  for (int pass = 0; pass < 16; ++pass) {
    const int o0 = (og << 7) + (pass << 3);
    float h[8];
#pragma unroll
    for (int j = 0; j < 8; ++j) h[j] = b1[o0 + j];
    const float* wrow = w1 + (size_t)o0 * NC;
#pragma unroll 4
    for (int c = 0; c < NC; ++c) {
      const float xv = __bfloat162float(xs[c][t]);
#pragma unroll
      for (int j = 0; j < 8; ++j) h[j] = fmaf(wrow[j * NC + c], xv, h[j]);
    }
    float p = 0.f;
#pragma unroll
    for (int j = 0; j < 8; ++j) p = fmaf(w2[o0 + j], fmaxf(h[j], 0.f), p);
    gacc += p;
  }
  __syncthreads();
  float* gr = reinterpret_cast<float*>(&xs[0][0]);
  gr[og * 64 + t] = gacc;
  __syncthreads();
  if (tid < 64) {
    const float s = gr[tid] + gr[64 + tid] + gr[128 + tid] + gr[192 + tid] + b2[0];
    g[b * NT + t0 + tid] = 1.f / (1.f + __expf(-s));
  }
}

// ---------------------------------------------------------------------------
// Per-b inclusive scan of g; centers = cum - 0.5*g; aligned_lengths output.
// ---------------------------------------------------------------------------
__global__ __launch_bounds__(256) void k_scan(const float* __restrict__ g,
                                              const int* __restrict__ len_fea,
                                              float* __restrict__ centers,
                                              float* __restrict__ out_len) {
  const int b = blockIdx.x;
  const int tid = threadIdx.x;
  const float* gb = g + b * NT;
  float v[8];
  {
    const float4 p0 = *reinterpret_cast<const float4*>(&gb[tid * 8]);
    const float4 p1 = *reinterpret_cast<const float4*>(&gb[tid * 8 + 4]);
    v[0] = p0.x; v[1] = p0.y; v[2] = p0.z; v[3] = p0.w;
    v[4] = p1.x; v[5] = p1.y; v[6] = p1.z; v[7] = p1.w;
  }
  float s = 0.f;
#pragma unroll
  for (int j = 0; j < 8; ++j) s += v[j];
  float wscan = s;
  const int lane = tid & 63, wid = tid >> 6;
#pragma unroll
  for (int off = 1; off < 64; off <<= 1) {
    const float o = __shfl_up(wscan, (unsigned)off, 64);
    if (lane >= off) wscan += o;
  }
  __shared__ float wsum[4];
  if (lane == 63) wsum[wid] = wscan;
  __syncthreads();
  float base = 0.f;
#pragma unroll
  for (int i = 0; i < 4; ++i)
    if (i < wid) base += wsum[i];
  float run = base + wscan - s;
  const int li = len_fea[b] - 1;
#pragma unroll
  for (int j = 0; j < 8; ++j) {
    const int t = tid * 8 + j;
    run += v[j];
    centers[b * NT + t] = run - 0.5f * v[j];
    if (t == li) out_len[b] = run;
  }
}

// ---------------------------------------------------------------------------
// Fused softmax stats + w materialization (bf16 [B][NL][NT]).
// ---------------------------------------------------------------------------
__global__ __launch_bounds__(256) void k_wstats(
    const float* __restrict__ centers, const int* __restrict__ len_fea,
    __hip_bfloat16* __restrict__ wbf) {
  const int b = blockIdx.x / NL;
  const int l = blockIdx.x % NL;
  const int tid = threadIdx.x;
  const int len = len_fea[b];
  const float pos = 0.5f + (float)l;
  const float* cb = centers + b * NT;
  const int t0 = tid * 8;

  float cv[8];
  {
    const float4 p0 = *reinterpret_cast<const float4*>(&cb[t0]);
    const float4 p1 = *reinterpret_cast<const float4*>(&cb[t0 + 4]);
    cv[0] = p0.x; cv[1] = p0.y; cv[2] = p0.z; cv[3] = p0.w;
    cv[4] = p1.x; cv[5] = p1.y; cv[6] = p1.z; cv[7] = p1.w;
  }
  float lg[8];
  float m = -3.0e38f;
#pragma unroll
  for (int j = 0; j < 8; ++j) {
    if (t0 + j < len) {
      const float d = cv[j] - pos;
      lg[j] = -d * d * kInvSigma2;
      m = fmaxf(m, lg[j]);
    } else {
      lg[j] = -3.0e38f;
    }
  }
  const int lane = tid & 63, wid = tid >> 6;
#pragma unroll
  for (int off = 32; off > 0; off >>= 1) m = fmaxf(m, __shfl_xor(m, off, 64));
  __shared__ float redm[4];
  if (lane == 0) redm[wid] = m;
  __syncthreads();
  const float M = fmaxf(fmaxf(redm[0], redm[1]), fmaxf(redm[2], redm[3]));

  float e[8];
  float ssum = 0.f;
#pragma unroll
  for (int j = 0; j < 8; ++j) {
    e[j] = (t0 + j < len) ? __expf(lg[j] - M) : 0.f;
    ssum += e[j];
  }
#pragma unroll
  for (int off = 32; off > 0; off >>= 1) ssum += __shfl_xor(ssum, off, 64);
  __shared__ float reds[4];
  if (lane == 0) reds[wid] = ssum;
  __syncthreads();
  const float rinv = 1.f / (reds[0] + reds[1] + reds[2] + reds[3]);

  bf16x8 o;
#pragma unroll
  for (int j = 0; j < 8; ++j) o[j] = (__bf16)(e[j] * rinv);
  *reinterpret_cast<bf16x8*>(&wbf[((size_t)b * NL + l) * NT + t0]) = o;
}

// ---------------------------------------------------------------------------
// MFMA out-kernel: out[b,l,c] = sum_t w[l,t]*x[c,t].
// Block = 4 waves, K(t)-split 4-way, LDS reduce (padded).
// ---------------------------------------------------------------------------
__global__ __launch_bounds__(256) void k_out_mfma(
    const float* __restrict__ x, const __hip_bfloat16* __restrict__ wbf,
    float* __restrict__ out) {
  __shared__ float red[3][64][41];
  const int blk = blockIdx.x;
  const int b = blk >> 4;
  const int c0 = (blk & 15) << 5;
  const int tid = threadIdx.x;
  const int w = tid >> 6;
  const int lane = tid & 63;
  const int ln = tid & 15;
  const int kg = lane >> 4;
  const int tbase = w << 9;

  f32x4 acc[5][2];
#pragma unroll
  for (int lt = 0; lt < 5; ++lt)
#pragma unroll
    for (int nt = 0; nt < 2; ++nt) acc[lt][nt] = (f32x4){0.f, 0.f, 0.f, 0.f};

  const __hip_bfloat16* abase =
      wbf + ((size_t)b * NL + ln) * NT + tbase + (kg << 3);
  const float* bbase = x + ((size_t)b * NC + c0 + ln) * NT + tbase + (kg << 3);

#pragma unroll 4
  for (int ks = 0; ks < 16; ++ks) {
    const int ck = ks << 5;
    bf16x8 bfrag[2];
#pragma unroll
    for (int nt = 0; nt < 2; ++nt) {
      const float4 p0 =
          *reinterpret_cast<const float4*>(bbase + nt * 16 * NT + ck);
      const float4 p1 =
          *reinterpret_cast<const float4*>(bbase + nt * 16 * NT + ck + 4);
      bf16x8 v;
      v[0] = (__bf16)p0.x; v[1] = (__bf16)p0.y;
      v[2] = (__bf16)p0.z; v[3] = (__bf16)p0.w;
      v[4] = (__bf16)p1.x; v[5] = (__bf16)p1.y;
      v[6] = (__bf16)p1.z; v[7] = (__bf16)p1.w;
      bfrag[nt] = v;
    }
#pragma unroll
    for (int lt = 0; lt < 5; ++lt) {
      const bf16x8 af =
          *reinterpret_cast<const bf16x8*>(abase + lt * 16 * NT + ck);
      acc[lt][0] = __builtin_amdgcn_mfma_f32_16x16x32_bf16(af, bfrag[0],
                                                           acc[lt][0], 0, 0, 0);
      acc[lt][1] = __builtin_amdgcn_mfma_f32_16x16x32_bf16(af, bfrag[1],
                                                           acc[lt][1], 0, 0, 0);
    }
  }

  if (w > 0) {
#pragma unroll
    for (int lt = 0; lt < 5; ++lt)
#pragma unroll
      for (int nt = 0; nt < 2; ++nt)
#pragma unroll
        for (int j = 0; j < 4; ++j)
          red[w - 1][lane][lt * 8 + nt * 4 + j] = acc[lt][nt][j];
  }
  __syncthreads();
  if (w == 0) {
#pragma unroll
    for (int lt = 0; lt < 5; ++lt)
#pragma unroll
      for (int nt = 0; nt < 2; ++nt)
#pragma unroll
        for (int j = 0; j < 4; ++j) {
          float s = acc[lt][nt][j];
#pragma unroll
          for (int i = 0; i < 3; ++i) s += red[i][lane][lt * 8 + nt * 4 + j];
          const int l = lt * 16 + (kg << 2) + j;
          out[((size_t)b * NL + l) * NC + c0 + nt * 16 + ln] = s;
        }
  }
}

// ---------------------------------------------------------------------------
// Fallback stats + out (VALU path).
// ---------------------------------------------------------------------------
__global__ __launch_bounds__(256) void k_stats(const float* __restrict__ centers,
                                               const int* __restrict__ len_fea,
                                               float* __restrict__ rmax,
                                               float* __restrict__ rinv) {
  const int b = blockIdx.x / NL;
  const int l = blockIdx.x % NL;
  const int tid = threadIdx.x;
  const int len = len_fea[b];
  const float pos = 0.5f + (float)l;
  const float* cb = centers + b * NT;
  float lg[8];
  float m = -3.0e38f;
  const int t0 = tid * 8;
#pragma unroll
  for (int j = 0; j < 8; ++j) {
    const int t = t0 + j;
    if (t < len) {
      const float d = cb[t] - pos;
      lg[j] = -d * d * kInvSigma2;
      m = fmaxf(m, lg[j]);
    } else {
      lg[j] = -3.0e38f;
    }
  }
  const int lane = tid & 63, wid = tid >> 6;
#pragma unroll
  for (int off = 32; off > 0; off >>= 1) m = fmaxf(m, __shfl_xor(m, off, 64));
  __shared__ float redm[4];
  if (lane == 0) redm[wid] = m;
  __syncthreads();
  const float M = fmaxf(fmaxf(redm[0], redm[1]), fmaxf(redm[2], redm[3]));
  float ssum = 0.f;
#pragma unroll
  for (int j = 0; j < 8; ++j) {
    if (t0 + j < len) ssum += __expf(lg[j] - M);
  }
#pragma unroll
  for (int off = 32; off > 0; off >>= 1) ssum += __shfl_xor(ssum, off, 64);
  __shared__ float reds[4];
  if (lane == 0) reds[wid] = ssum;
  __syncthreads();
  if (tid == 0) {
    const float S = reds[0] + reds[1] + reds[2] + reds[3];
    rmax[blockIdx.x] = M;
    rinv[blockIdx.x] = 1.f / S;
  }
}

__global__ __launch_bounds__(128) void k_out(const float* __restrict__ x,
                                             const int* __restrict__ len_fea,
                                             const float* __restrict__ centers,
                                             const float* __restrict__ rmax,
                                             const float* __restrict__ rinv,
                                             float* __restrict__ out) {
  __shared__ float xsh[128][65];
  __shared__ float wsh[20][64];
  const int blk = blockIdx.x;
  const int b = blk >> 4;
  const int l0 = ((blk >> 2) & 3) * 20;
  const int c0 = (blk & 3) * 128;
  const int tid = threadIdx.x;
  const int len = len_fea[b];
  float acc[20];
#pragma unroll
  for (int l = 0; l < 20; ++l) acc[l] = 0.f;

  for (int t0 = 0; t0 < NT; t0 += 64) {
    __syncthreads();
    {
      const int tl = (tid & 15) << 2;
      const int r0 = tid >> 4;
      for (int r = r0; r < 128; r += 8) {
        const float4 v = *reinterpret_cast<const float4*>(
            &x[((size_t)b * NC + c0 + r) * NT + t0 + tl]);
        float* p = &xsh[r][tl];
        p[0] = v.x; p[1] = v.y; p[2] = v.z; p[3] = v.w;
      }
    }
#pragma unroll
    for (int k = 0; k < 10; ++k) {
      const int idx = k * 128 + tid;
      const int l = idx >> 6;
      const int tt = idx & 63;
      float wv = 0.f;
      if (t0 + tt < len) {
        const float d = centers[b * NT + t0 + tt] - (0.5f + (float)(l0 + l));
        wv = __expf(-d * d * kInvSigma2 - rmax[b * NL + l0 + l]) *
             rinv[b * NL + l0 + l];
      }
      wsh[l][tt] = wv;
    }
    __syncthreads();
#pragma unroll 4
    for (int tt = 0; tt < 64; ++tt) {
      const float xv = xsh[tid][tt];
#pragma unroll
      for (int l = 0; l < 20; ++l) acc[l] = fmaf(wsh[l][tt], xv, acc[l]);
    }
  }
#pragma unroll
  for (int l = 0; l < 20; ++l)
    out[((size_t)b * NL + l0 + l) * NC + c0 + tid] = acc[l];
}

// ---------------------------------------------------------------------------
extern "C" void kernel_launch(void* const* d_in, const int* in_sizes, int n_in,
                              void* d_out, int out_size, void* d_ws, size_t ws_size,
                              hipStream_t stream) {
  const float* x = (const float*)d_in[0];
  const int* len_fea = (const int*)d_in[1];
  const float* w1 = (const float*)d_in[2];
  const float* b1 = (const float*)d_in[3];
  const float* w2 = (const float*)d_in[4];
  const float* b2 = (const float*)d_in[5];

  float* out = (float*)d_out;                   // [NB][NL][NC]
  float* out_len = out + (size_t)NB * NL * NC;  // [NB]

  float* ws = (float*)d_ws;
  float* g = ws;                                // [NB][NT]
  float* centers = ws + NB * NT;                // [NB][NT]
  float* rmax = ws + 2 * NB * NT;               // [NB*NL] (fallback)
  float* rinv = rmax + NB * NL;                 // [NB*NL] (fallback)
  __hip_bfloat16* w1p = (__hip_bfloat16*)(rinv + NB * NL);    // [512*512] packed
  __hip_bfloat16* wbf = w1p + (size_t)NC * NC;                // [NB][NL][NT]

  const size_t need_mid = (size_t)(2 * NB * NT + 2 * NB * NL) * 4 +
                          (size_t)NC * NC * 2;
  const size_t need_full = need_mid + (size_t)NB * NL * NT * 2;

  if (ws_size >= need_full) {
    k_w1p<<<(NC * NC) / 2048, 256, 0, stream>>>(w1, w1p);
    k_g_mfma<<<NB * 16, 512, 0, stream>>>(x, w1p, b1, w2, b2, g);
    k_scan<<<NB, 256, 0, stream>>>(g, len_fea, centers, out_len);
    k_wstats<<<NB * NL, 256, 0, stream>>>(centers, len_fea, wbf);
    k_out_mfma<<<NB * 16, 256, 0, stream>>>(x, wbf, out);
  } else if (ws_size >= need_mid) {
    k_w1p<<<(NC * NC) / 2048, 256, 0, stream>>>(w1, w1p);
    k_g_mfma<<<NB * 16, 512, 0, stream>>>(x, w1p, b1, w2, b2, g);
    k_scan<<<NB, 256, 0, stream>>>(g, len_fea, centers, out_len);
    k_stats<<<NB * NL, 256, 0, stream>>>(centers, len_fea, rmax, rinv);
    k_out<<<NB * 16, 128, 0, stream>>>(x, len_fea, centers, rmax, rinv, out);
  } else {
    k_g_slow<<<NB * 32, 256, 0, stream>>>(x, w1, b1, w2, b2, g);
    k_scan<<<NB, 256, 0, stream>>>(g, len_fea, centers, out_len);
    k_stats<<<NB * NL, 256, 0, stream>>>(centers, len_fea, rmax, rinv);
    k_out<<<NB * 16, 128, 0, stream>>>(x, len_fea, centers, rmax, rinv, out);
  }
}